// Round 1
// 112.803 us; speedup vs baseline: 1.0070x; 1.0070x over previous
//
#include <hip/hip_runtime.h>

#define NN 1024     // nodes
#define HD 128      // hidden
#define NHEAD 8
#define DHEAD 16
#define NE 32768    // edges
#define MAXDEG 128  // in-degree cap; Poisson(32) max ~70 for this input

// ---------------- workspace layout (bytes) ----------------
// cntIn  : 0       4 KB   in-degree counters        (memset 0)
// adjBit : 4096    128 KB outgoing-adjacency bitmap (memset 0)
// byDst  : 135168  512 KB incoming edges bucketed by dst, packed (src<<16)|e
//
// R6: grid.sync ~75 µs on 8-XCD MI355X — kernel boundary is the cheap sync.
// R8: dense per-node LDS scores cost 100 µs; ~1 position/node has content.
// R9: sparse per-node factorization works; harness poison fill (~43 µs) is
//     the fixed floor. R10: vectorize the qk phase (was 128 scalar loads/thread).
// R11: parallelize dedup+softmax — was 8 serial threads doing O(ns^2)
//      dependent-LDS scans (the longest dependence chain in the kernel);
//      now O(ns) parallel dedup + 16-lane-per-head shfl reductions.

// ---------- K0: bucket incoming edges + build outgoing bitmap ----------
__global__ __launch_bounds__(256) void bucket_kernel(
    const int* __restrict__ src, const int* __restrict__ dst,
    int* __restrict__ cntIn, unsigned int* __restrict__ adjBit,
    int* __restrict__ byDst) {
  int e = blockIdx.x * 256 + threadIdx.x;
  int s = src[e], d = dst[e];
  atomicOr(&adjBit[s * 32 + (d >> 5)], 1u << (d & 31));
  int si = atomicAdd(&cntIn[d], 1);
  if (si < MAXDEG) byDst[d * MAXDEG + si] = (s << 16) | e;
}

// ---------- K1: one block per node, fully sparse ----------
__global__ __launch_bounds__(128) void node_kernel(
    const float* __restrict__ x, const float* __restrict__ ea,
    const float* __restrict__ W, const float* __restrict__ bias,
    const float* __restrict__ Wo, const float* __restrict__ ob,
    const int* __restrict__ cntIn, const unsigned int* __restrict__ adjBit,
    const int* __restrict__ byDst, float* __restrict__ out) {
  const int b = blockIdx.x, t = threadIdx.x;
  const int w = t >> 6, lane = t & 63;
  const int hn = lane >> 3, hc = lane & 7;     // head, 16-elem chunk

  __shared__ float xs[HD], qs[HD], aos[HD];
  __shared__ float qks[NHEAD * 136];           // qk rows; reused for agg
  __shared__ unsigned int aw[32];              // allowed-position bitmap
  __shared__ int eList[MAXDEG];                // survivor edge ids
  __shared__ unsigned short ePos[MAXDEG];      // survivor src positions
  __shared__ short fIdx[MAXDEG];               // primary index per survivor
  __shared__ float eDot[MAXDEG * NHEAD];       // raw dots -> final attn wts
  __shared__ float eAttn[MAXDEG * NHEAD];      // primary scores
  __shared__ float qbv[NHEAD];
  __shared__ int nSurv, allowedCnt, ndCnt;

  if (t < 32) aw[t] = adjBit[b * 32 + t];
  if (t == 0) { nSurv = 0; ndCnt = 0; }
  xs[t] = x[(size_t)b * HD + t];
  // prefetch degree early (independent scalar load)
  const int degI = min(cntIn[b], MAXDEG);
  __syncthreads();
  if (t == 0) aw[b >> 5] |= 1u << (b & 31);    // self always allowed
  __syncthreads();
  if (t < 32) {
    int pc = __popc(aw[t]);
    #pragma unroll
    for (int off = 16; off; off >>= 1) pc += __shfl_xor(pc, off, 32);
    if (t == 0) allowedCnt = pc;
  }

  // ---- survivor build (t<degI) overlapped with q-projection (all t) ----
  if (t < degI) {
    int pk = byDst[b * MAXDEG + t];
    int e = pk & 0xFFFF, s = pk >> 16;
    if ((aw[s >> 5] >> (s & 31)) & 1) {
      int k = atomicAdd(&nSurv, 1);
      eList[k] = e; ePos[k] = (unsigned short)s;
    }
  }
  // ---- q[b,t] = bq[t] + Wq[t,:]·x  (weights L1/L2-hot across blocks) ----
  {
    const float4* wr = (const float4*)(W + (size_t)t * HD);
    const float4* xv4 = (const float4*)xs;
    float acc = bias[t];
    #pragma unroll
    for (int k = 0; k < HD / 4; k++) {
      float4 wv = wr[k]; float4 xv = xv4[k];
      acc += xv.x * wv.x + xv.y * wv.y + xv.z * wv.z + xv.w * wv.w;
    }
    qs[t] = acc;
    float p = acc * bias[HD + t];              // qb = q·bk per head
    #pragma unroll
    for (int off = 8; off; off >>= 1) p += __shfl_xor(p, off, 16);
    if ((t & 15) == 0) qbv[t >> 4] = p;
  }
  __syncthreads();

  // ---- qk phase, vectorized: thread t -> heads {np, np+4}, float4 chunk c4 ----
  // qk4[n][c4] = sum_d qs[n*16+d] * wk4[(n*16+d)*32 + c4]
  {
    const float4* wk4 = (const float4*)(W + HD * HD);
    const int c4 = t & 31, np = t >> 5;
    float4* qks4 = (float4*)qks;               // 136 floats = 34 float4/row
    #pragma unroll
    for (int h = 0; h < 2; h++) {
      const int n = np + h * 4;
      float4 acc = make_float4(0.f, 0.f, 0.f, 0.f);
      #pragma unroll
      for (int d = 0; d < DHEAD; d++) {
        float qv = qs[n * DHEAD + d];
        float4 wv = wk4[(n * DHEAD + d) * 32 + c4];
        acc.x += qv * wv.x; acc.y += qv * wv.y;
        acc.z += qv * wv.z; acc.w += qv * wv.w;
      }
      qks4[n * 34 + c4] = acc;
    }
  }
  __syncthreads();
  const int ns = nSurv;

  // ---- 8-head dots for survivor edges (one wave per edge) ----
  float frag[16];
  #pragma unroll
  for (int i = 0; i < 16; i++) frag[i] = qks[hn * 136 + hc * 16 + i];
  for (int k = w; k < ns; k += 2) {
    const float4* ap = (const float4*)(ea + (size_t)eList[k] * HD + hc * 16);
    float p = 0.f;
    #pragma unroll
    for (int i = 0; i < 4; i++) {
      float4 av = ap[i];
      p += av.x * frag[i * 4 + 0] + av.y * frag[i * 4 + 1] +
           av.z * frag[i * 4 + 2] + av.w * frag[i * 4 + 3];
    }
    p += __shfl_xor(p, 1);
    p += __shfl_xor(p, 2);
    p += __shfl_xor(p, 4);
    if (hc == 0) eDot[k * NHEAD + hn] = p;
  }
  __syncthreads();

  // ---- parallel dedup: fIdx[k] = first survivor with same src position ----
  // Fixed-trip backward loop: independent LDS reads pipeline (the old serial
  // 8-thread version was ~2000 DEPENDENT LDS reads on 8 of 128 lanes).
  if (t < ns) {
    const int my = ePos[t];
    int f = t;
    for (int j = t - 1; j >= 0; j--)
      if (ePos[j] == my) f = j;
    fIdx[t] = (short)f;
    if (f == t) {
      atomicAdd(&ndCnt, 1);                    // count distinct positions
    } else {
      #pragma unroll
      for (int n = 0; n < NHEAD; n++)          // fold duplicate dots (rare)
        atomicAdd(&eDot[f * NHEAD + n], eDot[t * NHEAD + n]);
    }
  }
  __syncthreads();

  // ---- per-head softmax: 16-lane group per head, shfl reductions ----
  // Head n lives entirely in one wave; per-head LDS slots are touched only
  // by its own group, so in-wave lockstep ordering suffices (no barrier
  // until the agg phase below).
  {
    const int n = t >> 4, l16 = t & 15;
    const int nd = ndCnt;
    const float qb = qbv[n];
    const float sb = qb * 0.25f;               // background score (no edge)
    float m = sb;
    for (int k = l16; k < ns; k += 16) {
      if (fIdx[k] == k) {
        float sc = (eDot[k * NHEAD + n] + qb) * 0.25f;
        eAttn[k * NHEAD + n] = sc;             // stash primary score
        m = fmaxf(m, sc);
      }
    }
    #pragma unroll
    for (int off = 8; off; off >>= 1) m = fmaxf(m, __shfl_xor(m, off, 16));
    float l = 0.f;
    for (int k = l16; k < ns; k += 16)
      if (fIdx[k] == k) l += expf(eAttn[k * NHEAD + n] - m);
    #pragma unroll
    for (int off = 8; off; off >>= 1) l += __shfl_xor(l, off, 16);
    l += (float)(allowedCnt - nd) * expf(sb - m);
    const float inv = 1.0f / l;
    // duplicates read their primary's score; write weights to eDot
    for (int k = l16; k < ns; k += 16)
      eDot[k * NHEAD + n] = expf(eAttn[fIdx[k] * NHEAD + n] - m) * inv;
  }
  __syncthreads();

  // ---- value agg: agg[n][t] = sum_surv attn[n]·ea[e][t] ----
  float aggr[NHEAD];
  #pragma unroll
  for (int n = 0; n < NHEAD; n++) aggr[n] = 0.f;
  for (int k = 0; k < ns; k++) {
    float av = ea[(size_t)eList[k] * HD + t];
    #pragma unroll
    for (int n = 0; n < NHEAD; n++) aggr[n] += eDot[k * NHEAD + n] * av;
  }
  __syncthreads();                             // qks reads done; safe to reuse
  #pragma unroll
  for (int n = 0; n < NHEAD; n++) qks[n * 136 + t] = aggr[n];
  __syncthreads();

  // ---- attn_out[t] = bv[t] + Wv[t,:]·agg[head(t)][:] ----
  {
    int nj = t >> 4;
    const float4* wvr = (const float4*)(W + 2 * HD * HD + (size_t)t * HD);
    const float4* ar = (const float4*)&qks[nj * 136];
    float acc = bias[2 * HD + t];
    #pragma unroll
    for (int k = 0; k < HD / 4; k++) {
      float4 wv = wvr[k]; float4 av = ar[k];
      acc += av.x * wv.x + av.y * wv.y + av.z * wv.z + av.w * wv.w;
    }
    aos[t] = acc;
  }
  __syncthreads();
  // ---- out[b,t] = bo[t] + Wo[t,:]·attn_out ----
  {
    const float4* wor = (const float4*)(Wo + (size_t)t * HD);
    const float4* av4 = (const float4*)aos;
    float acc2 = ob[t];
    #pragma unroll
    for (int k = 0; k < HD / 4; k++) {
      float4 wv = wor[k]; float4 av = av4[k];
      acc2 += av.x * wv.x + av.y * wv.y + av.z * wv.z + av.w * wv.w;
    }
    out[(size_t)b * HD + t] = acc2;
  }
}

extern "C" void kernel_launch(void* const* d_in, const int* in_sizes, int n_in,
                              void* d_out, int out_size, void* d_ws, size_t ws_size,
                              hipStream_t stream) {
  const float* x     = (const float*)d_in[0];
  const int*   eidx  = (const int*)d_in[1];
  const float* eattr = (const float*)d_in[2];
  const float* in_w  = (const float*)d_in[4];
  const float* in_b  = (const float*)d_in[5];
  const float* out_w = (const float*)d_in[6];
  const float* out_b = (const float*)d_in[7];
  float* out = (float*)d_out;

  const int* src = eidx;
  const int* dst = eidx + NE;

  char* ws = (char*)d_ws;
  int* cntIn            = (int*)(ws + 0);
  unsigned int* adjBit  = (unsigned int*)(ws + 4096);
  int* byDst            = (int*)(ws + 135168);

  hipMemsetAsync(ws, 0, 135168, stream);   // cntIn + adjBit (132 KB)
  bucket_kernel<<<NE / 256, 256, 0, stream>>>(src, dst, cntIn, adjBit, byDst);
  node_kernel<<<NN, 128, 0, stream>>>(x, eattr, in_w, in_b, out_w, out_b,
                                      cntIn, adjBit, byDst, out);
}

// Round 3
// 107.201 us; speedup vs baseline: 1.0596x; 1.0523x over previous
//
#include <hip/hip_runtime.h>

#define NN 1024     // nodes
#define HD 128      // hidden
#define NHEAD 8
#define DHEAD 16
#define NE 32768    // edges
#define MAXDEG 128  // in-degree cap; Poisson(32) max ~70 for this input
#define PRE 16      // register-prefetch depth; survivors ~Poisson(1), 16 >> p99.999

// ---------------- workspace layout (bytes) ----------------
// cntIn  : 0       64 KB  in-degree counters, ONE PER CACHELINE (stride 16 ints)
// adjBit : 65536   128 KB outgoing-adjacency bitmap (memset 0)
// byDst  : 196608  512 KB incoming edges bucketed by dst, packed (src<<16)|e
//
// R6: grid.sync ~75 µs on 8-XCD MI355X — kernel boundary is the cheap sync.
// R8: dense per-node LDS scores cost 100 µs; ~1 position/node has content.
// R9: sparse per-node factorization works; harness poison fill (~43 µs/iter,
//     HBM-roofline on 268 MB) is fixed. R10: vectorized qk phase.
// R11: parallel dedup+softmax — NEUTRAL. Lesson: per-block serial chains are
//      TLP-hidden at 8 waves/CU; only aggregate-throughput costs matter.
// R12: cntIn cacheline padding + ea prefetch — CRASHED: prefetch read
//      eList[0] when ns==0 (uninit LDS -> wild address). ns ~ Poisson(1);
//      37% of nodes have ZERO survivors. Guard the ADDRESS, not just the use.
// R13: fix = safe edge id 0 for inactive prefetch slots; PRE 64->16 (was
//      sized off in-degree, but survivors are the bidirectional subset).

// ---------- K0: bucket incoming edges + build outgoing bitmap ----------
__global__ __launch_bounds__(256) void bucket_kernel(
    const int* __restrict__ src, const int* __restrict__ dst,
    int* __restrict__ cntIn, unsigned int* __restrict__ adjBit,
    int* __restrict__ byDst) {
  int e = blockIdx.x * 256 + threadIdx.x;
  int s = src[e], d = dst[e];
  atomicOr(&adjBit[s * 32 + (d >> 5)], 1u << (d & 31));
  int si = atomicAdd(&cntIn[d << 4], 1);       // 1 counter per cacheline
  if (si < MAXDEG) byDst[d * MAXDEG + si] = (s << 16) | e;
}

// ---------- K1: one block per node, fully sparse ----------
__global__ __launch_bounds__(128) void node_kernel(
    const float* __restrict__ x, const float* __restrict__ ea,
    const float* __restrict__ W, const float* __restrict__ bias,
    const float* __restrict__ Wo, const float* __restrict__ ob,
    const int* __restrict__ cntIn, const unsigned int* __restrict__ adjBit,
    const int* __restrict__ byDst, float* __restrict__ out) {
  const int b = blockIdx.x, t = threadIdx.x;
  const int w = t >> 6, lane = t & 63;
  const int hn = lane >> 3, hc = lane & 7;     // head, 16-elem chunk

  __shared__ float xs[HD], qs[HD], aos[HD];
  __shared__ float qks[NHEAD * 136];           // qk rows; reused for agg
  __shared__ unsigned int aw[32];              // allowed-position bitmap
  __shared__ int eList[MAXDEG];                // survivor edge ids
  __shared__ unsigned short ePos[MAXDEG];      // survivor src positions
  __shared__ short fIdx[MAXDEG];               // primary index per survivor
  __shared__ float eDot[MAXDEG * NHEAD];       // raw dots -> final attn wts
  __shared__ float eAttn[MAXDEG * NHEAD];      // primary scores
  __shared__ float qbv[NHEAD];
  __shared__ int nSurv, allowedCnt, ndCnt;

  if (t < 32) aw[t] = adjBit[b * 32 + t];
  if (t == 0) { nSurv = 0; ndCnt = 0; }
  xs[t] = x[(size_t)b * HD + t];
  // prefetch degree early (independent scalar load)
  const int degI = min(cntIn[b << 4], MAXDEG);
  __syncthreads();
  if (t == 0) aw[b >> 5] |= 1u << (b & 31);    // self always allowed
  __syncthreads();
  if (t < 32) {
    int pc = __popc(aw[t]);
    #pragma unroll
    for (int off = 16; off; off >>= 1) pc += __shfl_xor(pc, off, 32);
    if (t == 0) allowedCnt = pc;
  }

  // ---- survivor build (t<degI) overlapped with q-projection (all t) ----
  if (t < degI) {
    int pk = byDst[b * MAXDEG + t];
    int e = pk & 0xFFFF, s = pk >> 16;
    if ((aw[s >> 5] >> (s & 31)) & 1) {
      int k = atomicAdd(&nSurv, 1);
      eList[k] = e; ePos[k] = (unsigned short)s;
    }
  }
  // ---- q[b,t] = bq[t] + Wq[t,:]·x  (weights L1/L2-hot across blocks) ----
  {
    const float4* wr = (const float4*)(W + (size_t)t * HD);
    const float4* xv4 = (const float4*)xs;
    float acc = bias[t];
    #pragma unroll
    for (int k = 0; k < HD / 4; k++) {
      float4 wv = wr[k]; float4 xv = xv4[k];
      acc += xv.x * wv.x + xv.y * wv.y + xv.z * wv.z + xv.w * wv.w;
    }
    qs[t] = acc;
    float p = acc * bias[HD + t];              // qb = q·bk per head
    #pragma unroll
    for (int off = 8; off; off >>= 1) p += __shfl_xor(p, off, 16);
    if ((t & 15) == 0) qbv[t >> 4] = p;
  }
  __syncthreads();

  // ---- qk phase, vectorized: thread t -> heads {np, np+4}, float4 chunk c4 ----
  // qk4[n][c4] = sum_d qs[n*16+d] * wk4[(n*16+d)*32 + c4]
  {
    const float4* wk4 = (const float4*)(W + HD * HD);
    const int c4 = t & 31, np = t >> 5;
    float4* qks4 = (float4*)qks;               // 136 floats = 34 float4/row
    #pragma unroll
    for (int h = 0; h < 2; h++) {
      const int n = np + h * 4;
      float4 acc = make_float4(0.f, 0.f, 0.f, 0.f);
      #pragma unroll
      for (int d = 0; d < DHEAD; d++) {
        float qv = qs[n * DHEAD + d];
        float4 wv = wk4[(n * DHEAD + d) * 32 + c4];
        acc.x += qv * wv.x; acc.y += qv * wv.y;
        acc.z += qv * wv.z; acc.w += qv * wv.w;
      }
      qks4[n * 34 + c4] = acc;
    }
  }
  __syncthreads();
  const int ns = nSurv;

  // ---- register-prefetch ea[e][t] for the value agg (in flight across
  //      the dots/dedup/softmax phases). Edge id 0 is a SAFE dummy for
  //      inactive slots (ns can be 0 — eList[0] may be uninitialized!) ----
  float pre[PRE];
  #pragma unroll
  for (int k = 0; k < PRE; k++) {
    int e = (k < ns) ? eList[k] : 0;
    pre[k] = ea[(size_t)e * HD + t];
  }

  // ---- 8-head dots for survivor edges (one wave per edge) ----
  float frag[16];
  #pragma unroll
  for (int i = 0; i < 16; i++) frag[i] = qks[hn * 136 + hc * 16 + i];
  for (int k = w; k < ns; k += 2) {
    const float4* ap = (const float4*)(ea + (size_t)eList[k] * HD + hc * 16);
    float p = 0.f;
    #pragma unroll
    for (int i = 0; i < 4; i++) {
      float4 av = ap[i];
      p += av.x * frag[i * 4 + 0] + av.y * frag[i * 4 + 1] +
           av.z * frag[i * 4 + 2] + av.w * frag[i * 4 + 3];
    }
    p += __shfl_xor(p, 1);
    p += __shfl_xor(p, 2);
    p += __shfl_xor(p, 4);
    if (hc == 0) eDot[k * NHEAD + hn] = p;
  }
  __syncthreads();

  // ---- parallel dedup: fIdx[k] = first survivor with same src position ----
  if (t < ns) {
    const int my = ePos[t];
    int f = t;
    for (int j = t - 1; j >= 0; j--)
      if (ePos[j] == my) f = j;
    fIdx[t] = (short)f;
    if (f == t) {
      atomicAdd(&ndCnt, 1);                    // count distinct positions
    } else {
      #pragma unroll
      for (int n = 0; n < NHEAD; n++)          // fold duplicate dots (rare)
        atomicAdd(&eDot[f * NHEAD + n], eDot[t * NHEAD + n]);
    }
  }
  __syncthreads();

  // ---- per-head softmax: 16-lane group per head, shfl reductions ----
  {
    const int n = t >> 4, l16 = t & 15;
    const int nd = ndCnt;
    const float qb = qbv[n];
    const float sb = qb * 0.25f;               // background score (no edge)
    float m = sb;
    for (int k = l16; k < ns; k += 16) {
      if (fIdx[k] == k) {
        float sc = (eDot[k * NHEAD + n] + qb) * 0.25f;
        eAttn[k * NHEAD + n] = sc;             // stash primary score
        m = fmaxf(m, sc);
      }
    }
    #pragma unroll
    for (int off = 8; off; off >>= 1) m = fmaxf(m, __shfl_xor(m, off, 16));
    float l = 0.f;
    for (int k = l16; k < ns; k += 16)
      if (fIdx[k] == k) l += expf(eAttn[k * NHEAD + n] - m);
    #pragma unroll
    for (int off = 8; off; off >>= 1) l += __shfl_xor(l, off, 16);
    l += (float)(allowedCnt - nd) * expf(sb - m);
    const float inv = 1.0f / l;
    // duplicates read their primary's score; write weights to eDot
    for (int k = l16; k < ns; k += 16)
      eDot[k * NHEAD + n] = expf(eAttn[fIdx[k] * NHEAD + n] - m) * inv;
  }
  __syncthreads();

  // ---- value agg from prefetched regs: agg[n][t] = sum_k attn[n]·pre[k] ----
  float aggr[NHEAD];
  #pragma unroll
  for (int n = 0; n < NHEAD; n++) aggr[n] = 0.f;
  #pragma unroll
  for (int k = 0; k < PRE; k++) {
    if (k < ns) {
      const float4* ed4 = (const float4*)&eDot[k * NHEAD];
      float4 a0 = ed4[0], a1 = ed4[1];
      float av = pre[k];
      aggr[0] += a0.x * av; aggr[1] += a0.y * av;
      aggr[2] += a0.z * av; aggr[3] += a0.w * av;
      aggr[4] += a1.x * av; aggr[5] += a1.y * av;
      aggr[6] += a1.z * av; aggr[7] += a1.w * av;
    }
  }
  for (int k = PRE; k < ns; k++) {             // tail (survivors > 16: ~never)
    float av = ea[(size_t)eList[k] * HD + t];
    #pragma unroll
    for (int n = 0; n < NHEAD; n++) aggr[n] += eDot[k * NHEAD + n] * av;
  }
  __syncthreads();                             // qks reads done; safe to reuse
  #pragma unroll
  for (int n = 0; n < NHEAD; n++) qks[n * 136 + t] = aggr[n];
  __syncthreads();

  // ---- attn_out[t] = bv[t] + Wv[t,:]·agg[head(t)][:] ----
  {
    int nj = t >> 4;
    const float4* wvr = (const float4*)(W + 2 * HD * HD + (size_t)t * HD);
    const float4* ar = (const float4*)&qks[nj * 136];
    float acc = bias[2 * HD + t];
    #pragma unroll
    for (int k = 0; k < HD / 4; k++) {
      float4 wv = wvr[k]; float4 av = ar[k];
      acc += av.x * wv.x + av.y * wv.y + av.z * wv.z + av.w * wv.w;
    }
    aos[t] = acc;
  }
  __syncthreads();
  // ---- out[b,t] = bo[t] + Wo[t,:]·attn_out ----
  {
    const float4* wor = (const float4*)(Wo + (size_t)t * HD);
    const float4* av4 = (const float4*)aos;
    float acc2 = ob[t];
    #pragma unroll
    for (int k = 0; k < HD / 4; k++) {
      float4 wv = wor[k]; float4 av = av4[k];
      acc2 += av.x * wv.x + av.y * wv.y + av.z * wv.z + av.w * wv.w;
    }
    out[(size_t)b * HD + t] = acc2;
  }
}

extern "C" void kernel_launch(void* const* d_in, const int* in_sizes, int n_in,
                              void* d_out, int out_size, void* d_ws, size_t ws_size,
                              hipStream_t stream) {
  const float* x     = (const float*)d_in[0];
  const int*   eidx  = (const int*)d_in[1];
  const float* eattr = (const float*)d_in[2];
  const float* in_w  = (const float*)d_in[4];
  const float* in_b  = (const float*)d_in[5];
  const float* out_w = (const float*)d_in[6];
  const float* out_b = (const float*)d_in[7];
  float* out = (float*)d_out;

  const int* src = eidx;
  const int* dst = eidx + NE;

  char* ws = (char*)d_ws;
  int* cntIn            = (int*)(ws + 0);        // 64 KB, stride-16 ints
  unsigned int* adjBit  = (unsigned int*)(ws + 65536);
  int* byDst            = (int*)(ws + 196608);

  hipMemsetAsync(ws, 0, 196608, stream);   // cntIn + adjBit (192 KB)
  bucket_kernel<<<NE / 256, 256, 0, stream>>>(src, dst, cntIn, adjBit, byDst);
  node_kernel<<<NN, 128, 0, stream>>>(x, eattr, in_w, in_b, out_w, out_b,
                                      cntIn, adjBit, byDst, out);
}